// Round 2
// baseline (812.938 us; speedup 1.0000x reference)
//
#include <hip/hip_runtime.h>

// GAT (2 layers, heads=1) + 2-layer MLP head. N=100000, E=3200000, D=128.
// Softmax stabilization uses a GLOBAL upper bound m̄_i = leaky(gmax_asrc + adst_i)
// (valid since leaky_relu is monotone); alpha is mathematically unchanged.

#define NEG 0.2f

__device__ __forceinline__ float lrelu(float x) { return x > 0.0f ? x : NEG * x; }

// order-preserving float<->uint encoding for atomicMax on floats
__device__ __forceinline__ unsigned fenc(float f) {
    unsigned u = __float_as_uint(f);
    return (u & 0x80000000u) ? ~u : (u | 0x80000000u);
}
__device__ __forceinline__ float fdec(unsigned e) {
    return (e & 0x80000000u) ? __uint_as_float(e & 0x7FFFFFFFu) : __uint_as_float(~e);
}

__global__ void k_init(unsigned* g) {
    if (threadIdx.x < 2) g[threadIdx.x] = 0u;  // enc(-NaN): below every real enc
}

// K1: h1 = x @ W1 (128->16), s1 = h1·a1s, d1 = h1·a1d, gmax1 = max(s1)
__global__ __launch_bounds__(256) void k_gemm1(
    const float* __restrict__ x, const float* __restrict__ W1,
    const float* __restrict__ a1s, const float* __restrict__ a1d,
    float* __restrict__ h1, float* __restrict__ s1, float* __restrict__ d1,
    unsigned* __restrict__ gmax, int N)
{
    __shared__ float sW[128 * 16];
    __shared__ float sx[64 * 132];   // 64 rows x 128, padded to 132 (bank spread)
    __shared__ float wm[4];
    int tid = threadIdx.x;
    for (int i = tid; i < 2048; i += 256) sW[i] = W1[i];
    int node0 = blockIdx.x * 64;
    for (int i = tid; i < 64 * 32; i += 256) {   // 2048 float4 coalesced loads
        int row = i >> 5, c4 = i & 31;
        int n = node0 + row;
        float4 v = make_float4(0.f, 0.f, 0.f, 0.f);
        if (n < N) v = ((const float4*)x)[(size_t)n * 32 + c4];
        *(float4*)&sx[row * 132 + c4 * 4] = v;
    }
    __syncthreads();

    int node = node0 + (tid >> 2);
    int grp  = tid & 3;                 // this thread computes h[grp*4 .. grp*4+3]
    const float* xr = &sx[(tid >> 2) * 132];
    float4 acc = make_float4(0.f, 0.f, 0.f, 0.f);
#pragma unroll 8
    for (int j = 0; j < 128; ++j) {
        float xv = xr[j];
        float4 w = *(const float4*)&sW[j * 16 + grp * 4];
        acc.x += xv * w.x; acc.y += xv * w.y; acc.z += xv * w.z; acc.w += xv * w.w;
    }
    float4 as = ((const float4*)a1s)[grp];
    float4 ad = ((const float4*)a1d)[grp];
    float sv = acc.x * as.x + acc.y * as.y + acc.z * as.z + acc.w * as.w;
    float dv = acc.x * ad.x + acc.y * ad.y + acc.z * ad.z + acc.w * ad.w;
    sv += __shfl_xor(sv, 1); sv += __shfl_xor(sv, 2);   // reduce over the 4-lane group
    dv += __shfl_xor(dv, 1); dv += __shfl_xor(dv, 2);
    if (node < N) {
        *(float4*)&h1[(size_t)node * 16 + grp * 4] = acc;
        if (grp == 0) { s1[node] = sv; d1[node] = dv; }
    }
    // block max of sv -> global gmax
    float m = (node < N) ? sv : -3.4e38f;
#pragma unroll
    for (int off = 32; off >= 1; off >>= 1) m = fmaxf(m, __shfl_xor(m, off));
    if ((tid & 63) == 0) wm[tid >> 6] = m;
    __syncthreads();
    if (tid == 0) {
        float b = fmaxf(fmaxf(wm[0], wm[1]), fmaxf(wm[2], wm[3]));
        atomicMax(gmax, fenc(b));
    }
}

// self-loop init: acc = w_self * h, den = w_self  (also serves as zero-init)
template <int F>
__global__ __launch_bounds__(256) void k_selfinit(
    const float* __restrict__ s, const float* __restrict__ d, const float* __restrict__ h,
    float* __restrict__ acc, float* __restrict__ den,
    const unsigned* __restrict__ gmaxp, int N)
{
    int n = blockIdx.x * 256 + threadIdx.x;
    if (n >= N) return;
    float g0 = fdec(*gmaxp);
    float sv = s[n], dd = d[n];
    float w = __expf(lrelu(sv + dd) - lrelu(g0 + dd));
    den[n] = w;
#pragma unroll
    for (int k = 0; k < F; ++k) acc[(size_t)n * 16 + k] = w * h[(size_t)n * 16 + k];
}

// edge pass: 16 lanes per edge; lane0 computes w, lanes 0..F-1 accumulate features
template <int F>
__global__ __launch_bounds__(256) void k_edge(
    const int* __restrict__ ei_src, const int* __restrict__ ei_dst,
    const float* __restrict__ sv, const float* __restrict__ dv,
    const float* __restrict__ h, float* __restrict__ acc, float* __restrict__ den,
    const unsigned* __restrict__ gmaxp, int E)
{
    int g = (blockIdx.x * 256 + threadIdx.x) >> 4;
    int k = threadIdx.x & 15;
    if (g >= E) return;
    int src = 0, dst = 0;
    float w = 0.f;
    if (k == 0) {
        src = ei_src[g];
        dst = ei_dst[g];
        float g0 = fdec(*gmaxp);
        float dd = dv[dst];
        float e    = lrelu(sv[src] + dd);
        float mbar = lrelu(g0 + dd);
        w = __expf(e - mbar);
    }
    src = __shfl(src, 0, 16);
    dst = __shfl(dst, 0, 16);
    w   = __shfl(w,   0, 16);
    if (k == 0) atomicAdd(&den[dst], w);
    if (k < F)  atomicAdd(&acc[(size_t)dst * 16 + k], w * h[(size_t)src * 16 + k]);
}

// K4: finish layer1 (normalize + bias + relu), fused layer-2 GEMM (16->10) + scores + gmax2
__global__ __launch_bounds__(256) void k_finish1(
    const float* __restrict__ acc1, const float* __restrict__ den1, const float* __restrict__ b1,
    const float* __restrict__ W2, const float* __restrict__ a2s, const float* __restrict__ a2d,
    float* __restrict__ h2, float* __restrict__ s2, float* __restrict__ d2,
    unsigned* __restrict__ gmax2, int N)
{
    __shared__ float sW[160], sb[16], sas[10], sad[10];
    __shared__ float wm[4];
    int tid = threadIdx.x;
    if (tid < 160) sW[tid] = W2[tid];
    if (tid < 16)  sb[tid] = b1[tid];
    if (tid < 10)  { sas[tid] = a2s[tid]; sad[tid] = a2d[tid]; }
    __syncthreads();
    int n = blockIdx.x * 256 + tid;
    float sval = -3.4e38f;
    if (n < N) {
        float inv = 1.0f / den1[n];
        float o[16];
#pragma unroll
        for (int k = 0; k < 16; ++k) {
            float v = acc1[(size_t)n * 16 + k] * inv + sb[k];
            o[k] = v > 0.0f ? v : 0.0f;
        }
        float hh[10];
#pragma unroll
        for (int r = 0; r < 10; ++r) hh[r] = 0.0f;
#pragma unroll
        for (int k = 0; k < 16; ++k)
#pragma unroll
            for (int r = 0; r < 10; ++r) hh[r] += o[k] * sW[k * 10 + r];
        float sv = 0.f, dv = 0.f;
#pragma unroll
        for (int r = 0; r < 10; ++r) { sv += hh[r] * sas[r]; dv += hh[r] * sad[r]; }
#pragma unroll
        for (int r = 0; r < 10; ++r) h2[(size_t)n * 16 + r] = hh[r];
        s2[n] = sv; d2[n] = dv;
        sval = sv;
    }
    float m = sval;
#pragma unroll
    for (int off = 32; off >= 1; off >>= 1) m = fmaxf(m, __shfl_xor(m, off));
    if ((tid & 63) == 0) wm[tid >> 6] = m;
    __syncthreads();
    if (tid == 0)
        atomicMax(gmax2, fenc(fmaxf(fmaxf(wm[0], wm[1]), fmaxf(wm[2], wm[3]))));
}

// K7: finish layer2 (normalize + bias, no relu) + MLP head -> out[N]
__global__ __launch_bounds__(256) void k_finish2(
    const float* __restrict__ acc2, const float* __restrict__ den2, const float* __restrict__ b2,
    const float* __restrict__ Wl1, const float* __restrict__ bl1,
    const float* __restrict__ Wl2, const float* __restrict__ bl2,
    float* __restrict__ out, int N)
{
    __shared__ float sW1[100], sb1[10], sW2[10], sb2g[10];
    int tid = threadIdx.x;
    if (tid < 100) sW1[tid] = Wl1[tid];
    if (tid < 10)  { sb1[tid] = bl1[tid]; sW2[tid] = Wl2[tid]; sb2g[tid] = b2[tid]; }
    __syncthreads();
    int n = blockIdx.x * 256 + tid;
    if (n >= N) return;
    float inv = 1.0f / den2[n];
    float o[10];
#pragma unroll
    for (int k = 0; k < 10; ++k) o[k] = acc2[(size_t)n * 16 + k] * inv + sb2g[k];
    float res = bl2[0];
#pragma unroll
    for (int r = 0; r < 10; ++r) {
        float v = sb1[r];
#pragma unroll
        for (int k = 0; k < 10; ++k) v += o[k] * sW1[k * 10 + r];
        float t = v > 0.0f ? v : 0.0f;
        res += t * sW2[r];
    }
    out[n] = res;
}

extern "C" void kernel_launch(void* const* d_in, const int* in_sizes, int n_in,
                              void* d_out, int out_size, void* d_ws, size_t ws_size,
                              hipStream_t stream)
{
    const float* x   = (const float*)d_in[0];
    const int*   ei  = (const int*)  d_in[1];   // [2][E] int32
    const float* W1  = (const float*)d_in[2];
    const float* a1s = (const float*)d_in[3];
    const float* a1d = (const float*)d_in[4];
    const float* b1  = (const float*)d_in[5];
    const float* W2  = (const float*)d_in[6];
    const float* a2s = (const float*)d_in[7];
    const float* a2d = (const float*)d_in[8];
    const float* b2  = (const float*)d_in[9];
    const float* Wl1 = (const float*)d_in[10];
    const float* bl1 = (const float*)d_in[11];
    const float* Wl2 = (const float*)d_in[12];
    const float* bl2 = (const float*)d_in[13];

    int N = in_sizes[0] / 128;
    int E = in_sizes[1] / 2;
    const int* ei_src = ei;
    const int* ei_dst = ei + E;

    // workspace layout (fp32). Total = 16 + N*53 floats ~= 21.2 MB.
    size_t need_bytes = (16 + (size_t)N * 53) * sizeof(float);
    if (ws_size < need_bytes) return;  // degrade to wrong-answer, never fault

    float*    ws    = (float*)d_ws;
    unsigned* gmax1 = (unsigned*)d_ws;       // [0]
    unsigned* gmax2 = gmax1 + 1;             // [1]
    size_t N16 = (size_t)N * 16;
    float* h1   = ws + 16;                   // N*16
    float* s1   = h1 + N16;                  // N
    float* d1   = s1 + N;                    // N
    float* acc1 = d1 + N;                    // N*16
    float* den1 = acc1 + N16;                // N
    float* h2   = den1 + N;                  // N*16 (stride 16, 10 used)
    float* s2   = h2 + N16;                  // N
    float* d2   = s2 + N;                    // N
    // layer-2 accumulators alias layer-1 buffers that are dead after k_finish1
    float* acc2 = h1;                        // N*16
    float* den2 = s1;                        // N

    int nblk = (N + 255) / 256;
    int eblk16 = (int)(((size_t)E * 16 + 255) / 256);

    hipLaunchKernelGGL(k_init, dim3(1), dim3(64), 0, stream, gmax1);
    hipLaunchKernelGGL(k_gemm1, dim3((N + 63) / 64), dim3(256), 0, stream,
                       x, W1, a1s, a1d, h1, s1, d1, gmax1, N);
    hipLaunchKernelGGL((k_selfinit<16>), dim3(nblk), dim3(256), 0, stream,
                       s1, d1, h1, acc1, den1, gmax1, N);
    hipLaunchKernelGGL((k_edge<16>), dim3(eblk16), dim3(256), 0, stream,
                       ei_src, ei_dst, s1, d1, h1, acc1, den1, gmax1, E);
    hipLaunchKernelGGL(k_finish1, dim3(nblk), dim3(256), 0, stream,
                       acc1, den1, b1, W2, a2s, a2d, h2, s2, d2, gmax2, N);
    hipLaunchKernelGGL((k_selfinit<10>), dim3(nblk), dim3(256), 0, stream,
                       s2, d2, h2, acc2, den2, gmax2, N);
    hipLaunchKernelGGL((k_edge<10>), dim3(eblk16), dim3(256), 0, stream,
                       ei_src, ei_dst, s2, d2, h2, acc2, den2, gmax2, E);
    hipLaunchKernelGGL(k_finish2, dim3(nblk), dim3(256), 0, stream,
                       acc2, den2, b2, Wl1, bl1, Wl2, bl2, (float*)d_out, N);
}

// Round 3
// 792.271 us; speedup vs baseline: 1.0261x; 1.0261x over previous
//
#include <hip/hip_runtime.h>

// GAT (2 layers, heads=1) + 2-layer MLP head. N=100000, E=3200000, D=128.
// R3: CSR (counting sort by dst) + gather-side aggregation, no fp32 atomics.
// Softmax stabilization uses a GLOBAL upper bound m̄_i = leaky(gmax_asrc + adst_i)
// (valid since leaky_relu is monotone); alpha is mathematically unchanged.

#define NEG 0.2f

__device__ __forceinline__ float lrelu(float x) { return x > 0.0f ? x : NEG * x; }

// order-preserving float<->uint encoding for atomicMax on floats
__device__ __forceinline__ unsigned fenc(float f) {
    unsigned u = __float_as_uint(f);
    return (u & 0x80000000u) ? ~u : (u | 0x80000000u);
}
__device__ __forceinline__ float fdec(unsigned e) {
    return (e & 0x80000000u) ? __uint_as_float(e & 0x7FFFFFFFu) : __uint_as_float(~e);
}

// zero gmax[2] and cnt/row_start[N+1]
__global__ __launch_bounds__(256) void k_init(unsigned* g, int* cnt, int N) {
    int i = blockIdx.x * 256 + threadIdx.x;
    if (i <= N) cnt[i] = 0;
    if (i < 2) g[i] = 0u;
}

// K1: h1 = x @ W1 (128->16), s1 = h1·a1s, d1 = h1·a1d, gmax1 = max(s1)
__global__ __launch_bounds__(256) void k_gemm1(
    const float* __restrict__ x, const float* __restrict__ W1,
    const float* __restrict__ a1s, const float* __restrict__ a1d,
    float* __restrict__ h1, float* __restrict__ s1, float* __restrict__ d1,
    unsigned* __restrict__ gmax, int N)
{
    __shared__ float sW[128 * 16];
    __shared__ float sx[64 * 132];   // 64 rows x 128, padded to 132
    __shared__ float wm[4];
    int tid = threadIdx.x;
    for (int i = tid; i < 2048; i += 256) sW[i] = W1[i];
    int node0 = blockIdx.x * 64;
    for (int i = tid; i < 64 * 32; i += 256) {
        int row = i >> 5, c4 = i & 31;
        int n = node0 + row;
        float4 v = make_float4(0.f, 0.f, 0.f, 0.f);
        if (n < N) v = ((const float4*)x)[(size_t)n * 32 + c4];
        *(float4*)&sx[row * 132 + c4 * 4] = v;
    }
    __syncthreads();

    int node = node0 + (tid >> 2);
    int grp  = tid & 3;
    const float* xr = &sx[(tid >> 2) * 132];
    float4 acc = make_float4(0.f, 0.f, 0.f, 0.f);
#pragma unroll 8
    for (int j = 0; j < 128; ++j) {
        float xv = xr[j];
        float4 w = *(const float4*)&sW[j * 16 + grp * 4];
        acc.x += xv * w.x; acc.y += xv * w.y; acc.z += xv * w.z; acc.w += xv * w.w;
    }
    float4 as = ((const float4*)a1s)[grp];
    float4 ad = ((const float4*)a1d)[grp];
    float sv = acc.x * as.x + acc.y * as.y + acc.z * as.z + acc.w * as.w;
    float dv = acc.x * ad.x + acc.y * ad.y + acc.z * ad.z + acc.w * ad.w;
    sv += __shfl_xor(sv, 1); sv += __shfl_xor(sv, 2);
    dv += __shfl_xor(dv, 1); dv += __shfl_xor(dv, 2);
    if (node < N) {
        *(float4*)&h1[(size_t)node * 16 + grp * 4] = acc;
        if (grp == 0) { s1[node] = sv; d1[node] = dv; }
    }
    float m = (node < N) ? sv : -3.4e38f;
#pragma unroll
    for (int off = 32; off >= 1; off >>= 1) m = fmaxf(m, __shfl_xor(m, off));
    if ((tid & 63) == 0) wm[tid >> 6] = m;
    __syncthreads();
    if (tid == 0) {
        float b = fmaxf(fmaxf(wm[0], wm[1]), fmaxf(wm[2], wm[3]));
        atomicMax(gmax, fenc(b));
    }
}

// ---- CSR build ----
__global__ __launch_bounds__(256) void k_count(const int* __restrict__ dst, int* __restrict__ cnt, int E) {
    int e = blockIdx.x * 256 + threadIdx.x;
    if (e < E) atomicAdd(&cnt[dst[e]], 1);
}

// block-local exclusive scan, 2048 elements/block (in-place safe: cnt==rs)
__global__ __launch_bounds__(256) void k_scan1(const int* __restrict__ cnt, int* __restrict__ rs,
                                               int* __restrict__ bsums, int N) {
    __shared__ int lds[256];
    int base = blockIdx.x * 2048;
    int tid = threadIdx.x;
    int v[8]; int s = 0;
#pragma unroll
    for (int i = 0; i < 8; ++i) {
        int idx = base + tid * 8 + i;
        int c = (idx < N) ? cnt[idx] : 0;
        v[i] = s; s += c;
    }
    lds[tid] = s; __syncthreads();
    for (int off = 1; off < 256; off <<= 1) {
        int t = (tid >= off) ? lds[tid - off] : 0;
        __syncthreads();
        lds[tid] += t;
        __syncthreads();
    }
    int excl = (tid > 0) ? lds[tid - 1] : 0;
#pragma unroll
    for (int i = 0; i < 8; ++i) {
        int idx = base + tid * 8 + i;
        if (idx < N) rs[idx] = v[i] + excl;
    }
    if (tid == 255) bsums[blockIdx.x] = lds[255];
}

__global__ void k_scan2(int* bsums, int nb) {
    if (threadIdx.x == 0) {
        int run = 0;
        for (int b = 0; b < nb; ++b) { int t = bsums[b]; bsums[b] = run; run += t; }
    }
}

__global__ __launch_bounds__(256) void k_scan3(int* __restrict__ rs, const int* __restrict__ bsums,
                                               int* __restrict__ nxt, int N, int E) {
    int i = blockIdx.x * 256 + threadIdx.x;
    if (i < N) {
        int v = rs[i] + bsums[i >> 11];
        rs[i] = v; nxt[i] = v;
    }
    if (i == N) rs[N] = E;
}

__global__ __launch_bounds__(256) void k_scatter(const int* __restrict__ esrc, const int* __restrict__ edst,
                                                 int* __restrict__ nxt, int* __restrict__ ssrc, int E) {
    int e = blockIdx.x * 256 + threadIdx.x;
    if (e >= E) return;
    int pos = atomicAdd(&nxt[edst[e]], 1);
    ssrc[pos] = esrc[e];
}

// ---- layer 1 aggregation, fused with normalize+bias+relu and layer-2 GEMM/scores ----
// 16 lanes per dst node.
__global__ __launch_bounds__(256) void k_agg1(
    const int* __restrict__ rs, const int* __restrict__ ssrc,
    const float* __restrict__ sv, const float* __restrict__ dvv,
    const float* __restrict__ h, const float* __restrict__ b1,
    const float* __restrict__ W2, const float* __restrict__ a2s, const float* __restrict__ a2d,
    float* __restrict__ h2, float* __restrict__ s2, float* __restrict__ d2,
    const unsigned* __restrict__ gmax1p, unsigned* __restrict__ gmax2, int N)
{
    __shared__ float sW[160], sb[16], sas[16], sad[16];
    __shared__ float wm[4];
    int tid = threadIdx.x;
    if (tid < 160) sW[tid] = W2[tid];
    if (tid < 16)  sb[tid] = b1[tid];
    if (tid < 10)  { sas[tid] = a2s[tid]; sad[tid] = a2d[tid]; }
    __syncthreads();

    int group = tid >> 4, k = tid & 15;
    int dst = blockIdx.x * 16 + group;
    float sval = -3.4e38f;
    if (dst < N) {
        float g0 = fdec(*gmax1p);
        float dd = dvv[dst];
        float mbar = lrelu(g0 + dd);
        // self loop
        float w = __expf(lrelu(sv[dst] + dd) - mbar);
        float acc = w * h[(size_t)dst * 16 + k];
        float den = w;
        int j = rs[dst], j1 = rs[dst + 1];
        for (; j < j1; ++j) {
            int src = ssrc[j];                       // broadcast within group
            float wj = __expf(lrelu(sv[src] + dd) - mbar);
            acc += wj * h[(size_t)src * 16 + k];     // 64B coalesced per group
            den += wj;
        }
        float o = acc / den + sb[k];
        o = fmaxf(o, 0.f);
        // 16->10 GEMM across the group: lane r (<10) computes hh[r]
        float hh = 0.f;
#pragma unroll
        for (int kk = 0; kk < 16; ++kk) {
            float ov = __shfl(o, kk, 16);
            if (k < 10) hh += ov * sW[kk * 10 + k];
        }
        float ts = (k < 10) ? hh * sas[k] : 0.f;
        float td = (k < 10) ? hh * sad[k] : 0.f;
#pragma unroll
        for (int off = 1; off < 16; off <<= 1) {
            ts += __shfl_xor(ts, off, 16);
            td += __shfl_xor(td, off, 16);
        }
        if (k < 10) h2[(size_t)dst * 16 + k] = hh;
        if (k == 0) { s2[dst] = ts; d2[dst] = td; }
        sval = ts;
    }
    // block max of s2 -> gmax2 (one atomic per block)
    float m = sval;
#pragma unroll
    for (int off = 32; off >= 1; off >>= 1) m = fmaxf(m, __shfl_xor(m, off));
    if ((tid & 63) == 0) wm[tid >> 6] = m;
    __syncthreads();
    if (tid == 0)
        atomicMax(gmax2, fenc(fmaxf(fmaxf(wm[0], wm[1]), fmaxf(wm[2], wm[3]))));
}

// ---- layer 2 aggregation, fused with normalize+bias and the MLP head -> out ----
__global__ __launch_bounds__(256) void k_agg2(
    const int* __restrict__ rs, const int* __restrict__ ssrc,
    const float* __restrict__ sv, const float* __restrict__ dvv,
    const float* __restrict__ h, const float* __restrict__ b2,
    const float* __restrict__ Wl1, const float* __restrict__ bl1,
    const float* __restrict__ Wl2, const float* __restrict__ bl2,
    const unsigned* __restrict__ gmax2p, float* __restrict__ out, int N)
{
    __shared__ float sW1[100], sb1[16], sW2[16], sb2[16];
    __shared__ float sbl2;
    int tid = threadIdx.x;
    if (tid < 100) sW1[tid] = Wl1[tid];
    if (tid < 10)  { sb1[tid] = bl1[tid]; sW2[tid] = Wl2[tid]; sb2[tid] = b2[tid]; }
    if (tid == 0)  sbl2 = bl2[0];
    __syncthreads();

    int group = tid >> 4, k = tid & 15;
    int dst = blockIdx.x * 16 + group;
    if (dst >= N) return;          // whole group exits together; shfls below are group-local
    bool fk = k < 10;
    float g0 = fdec(*gmax2p);
    float dd = dvv[dst];
    float mbar = lrelu(g0 + dd);
    float w = __expf(lrelu(sv[dst] + dd) - mbar);
    float acc = w * (fk ? h[(size_t)dst * 16 + k] : 0.f);
    float den = w;
    int j = rs[dst], j1 = rs[dst + 1];
    for (; j < j1; ++j) {
        int src = ssrc[j];
        float wj = __expf(lrelu(sv[src] + dd) - mbar);
        acc += wj * (fk ? h[(size_t)src * 16 + k] : 0.f);
        den += wj;
    }
    float o = acc / den + (fk ? sb2[k] : 0.f);   // layer-2 GAT output, no relu
    // MLP layer 1 (10->10): lane r computes v_r
    float v = fk ? sb1[k] : 0.f;
#pragma unroll
    for (int kk = 0; kk < 10; ++kk) {
        float ov = __shfl(o, kk, 16);
        if (fk) v += ov * sW1[kk * 10 + k];
    }
    float t = fmaxf(v, 0.f);
    float contrib = fk ? t * sW2[k] : 0.f;
#pragma unroll
    for (int off = 1; off < 16; off <<= 1) contrib += __shfl_xor(contrib, off, 16);
    if (k == 0) out[dst] = contrib + sbl2;
}

extern "C" void kernel_launch(void* const* d_in, const int* in_sizes, int n_in,
                              void* d_out, int out_size, void* d_ws, size_t ws_size,
                              hipStream_t stream)
{
    const float* x   = (const float*)d_in[0];
    const int*   ei  = (const int*)  d_in[1];   // [2][E] int32
    const float* W1  = (const float*)d_in[2];
    const float* a1s = (const float*)d_in[3];
    const float* a1d = (const float*)d_in[4];
    const float* b1  = (const float*)d_in[5];
    const float* W2  = (const float*)d_in[6];
    const float* a2s = (const float*)d_in[7];
    const float* a2d = (const float*)d_in[8];
    const float* b2  = (const float*)d_in[9];
    const float* Wl1 = (const float*)d_in[10];
    const float* bl1 = (const float*)d_in[11];
    const float* Wl2 = (const float*)d_in[12];
    const float* bl2 = (const float*)d_in[13];

    int N = in_sizes[0] / 128;
    int E = in_sizes[1] / 2;
    const int* ei_src = ei;
    const int* ei_dst = ei + E;

    // workspace layout: 16 + 34N floats, then (N+1)+N+64+E ints  (~28.2 MB)
    size_t need_bytes = (16 + (size_t)N * 34) * 4 + ((size_t)N * 2 + 65 + (size_t)E) * 4;
    if (ws_size < need_bytes) return;  // degrade to wrong-answer, never fault

    float*    ws    = (float*)d_ws;
    unsigned* gmax1 = (unsigned*)d_ws;       // [0]
    unsigned* gmax2 = gmax1 + 1;             // [1]
    size_t N16 = (size_t)N * 16;
    float* h1 = ws + 16;                     // N*16
    float* s1 = h1 + N16;                    // N
    float* d1 = s1 + N;                      // N
    float* h2 = d1 + N;                      // N*16 (stride 16, 10 used)
    float* s2 = h2 + N16;                    // N
    float* d2 = s2 + N;                      // N
    int* rs    = (int*)(d2 + N);             // N+1 (counts, then row starts)
    int* nxt   = rs + N + 1;                 // N
    int* bsums = nxt + N;                    // 64
    int* ssrc  = bsums + 64;                 // E

    int nblk16 = (N + 15) / 16;
    int eblk   = (E + 255) / 256;
    int nscan  = (N + 2047) / 2048;

    hipLaunchKernelGGL(k_init, dim3((N + 256) / 256), dim3(256), 0, stream, gmax1, rs, N);
    hipLaunchKernelGGL(k_gemm1, dim3((N + 63) / 64), dim3(256), 0, stream,
                       x, W1, a1s, a1d, h1, s1, d1, gmax1, N);
    hipLaunchKernelGGL(k_count, dim3(eblk), dim3(256), 0, stream, ei_dst, rs, E);
    hipLaunchKernelGGL(k_scan1, dim3(nscan), dim3(256), 0, stream, rs, rs, bsums, N);
    hipLaunchKernelGGL(k_scan2, dim3(1), dim3(64), 0, stream, bsums, nscan);
    hipLaunchKernelGGL(k_scan3, dim3((N + 256) / 256), dim3(256), 0, stream, rs, bsums, nxt, N, E);
    hipLaunchKernelGGL(k_scatter, dim3(eblk), dim3(256), 0, stream, ei_src, ei_dst, nxt, ssrc, E);
    hipLaunchKernelGGL(k_agg1, dim3(nblk16), dim3(256), 0, stream,
                       rs, ssrc, s1, d1, h1, b1, W2, a2s, a2d, h2, s2, d2, gmax1, gmax2, N);
    hipLaunchKernelGGL(k_agg2, dim3(nblk16), dim3(256), 0, stream,
                       rs, ssrc, s2, d2, h2, b2, Wl1, bl1, Wl2, bl2, gmax2, (float*)d_out, N);
}